// Round 19
// baseline (524.624 us; speedup 1.0000x reference)
//
#include <hip/hip_runtime.h>
#include <hip/hip_bf16.h>

#define DEVINL __device__ __forceinline__

typedef __attribute__((ext_vector_type(8))) short bf16x8;
typedef __attribute__((ext_vector_type(4))) float f32x4;

// f32 -> bf16 round-nearest-even (bit manipulation; values are finite)
DEVINL ushort f2bf(float f) {
  unsigned u = __float_as_uint(f);
  u += 0x7fffu + ((u >> 16) & 1u);
  return (ushort)(u >> 16);
}

DEVINL void gl_lds16(const void* g, void* lds) {
  __builtin_amdgcn_global_load_lds(
      (const __attribute__((address_space(1))) void*)g,
      (__attribute__((address_space(3))) void*)lds, 16, 0, 0);
}

DEVINL f32x4 mfma16(bf16x8 a, bf16x8 b, f32x4 c) {
  return __builtin_amdgcn_mfma_f32_16x16x32_bf16(a, b, c, 0, 0, 0);
}

// ======================= fused cast f32 -> bf16 (exact shapes) =======================
__global__ __launch_bounds__(256) void cast_all_kernel(const float4* __restrict__ x,
                                                       const float4* __restrict__ wq,
                                                       const float4* __restrict__ wk,
                                                       const float4* __restrict__ wv,
                                                       const float4* __restrict__ wo,
                                                       ushort4* __restrict__ xb,
                                                       ushort4* __restrict__ wqb,
                                                       ushort4* __restrict__ wkb,
                                                       ushort4* __restrict__ wvb,
                                                       ushort4* __restrict__ wob) {
  const int blk = (int)blockIdx.x;
  const float4* src;
  ushort4* dst;
  int base;
  if (blk < 2048)      { src = x;  dst = xb;  base = blk; }
  else if (blk < 3072) { src = wq; dst = wqb; base = blk - 2048; }
  else if (blk < 4096) { src = wk; dst = wkb; base = blk - 3072; }
  else if (blk < 5120) { src = wv; dst = wvb; base = blk - 4096; }
  else                 { src = wo; dst = wob; base = blk - 5120; }
  const int idx0 = base * 1024 + (int)threadIdx.x;
#pragma unroll
  for (int i = 0; i < 4; ++i) {
    const int idx = idx0 + i * 256;
    float4 v = src[idx];
    dst[idx] = make_ushort4(f2bf(v.x), f2bf(v.y), f2bf(v.z), f2bf(v.w));
  }
}

// ======================= QKV GEMM: 128^2 tile, graduated half-tile vmcnt (R14) ========
__global__ __launch_bounds__(256) void gemm_qkv(const ushort* __restrict__ A,
                                                const ushort* __restrict__ Bm,
                                                ushort* __restrict__ Qo,
                                                ushort* __restrict__ Ko,
                                                ushort* __restrict__ Vo,
                                                int M, int N, int K) {
  __shared__ __align__(16) ushort Al[2][8192];  // [f:8][ks:2][lane:64][8]
  __shared__ __align__(16) ushort Bl[2][8192];
  const int tid = (int)threadIdx.x;
  const int l = tid & 63, w = tid >> 6;
  const int wr = w >> 1, wc = w & 1;
  const int lr = l & 15, lg = l >> 4;

  // bijective XCD-chunked swizzle (nwg % 8 == 0)
  const int nwg = (int)(gridDim.x * gridDim.y);
  const int flat = (int)(blockIdx.y * gridDim.x + blockIdx.x);
  const int swz = (flat & 7) * (nwg >> 3) + (flat >> 3);
  const int bx = swz % (int)gridDim.x, by = swz / (int)gridDim.x;
  const int rowT = by * 128, colT = bx * 128;

  f32x4 acc[4][4] = {};

  // wave w stages slice f = fg*4 + w for each (ks, fg); 8 instr/thread per tile
  auto stage = [&](int kt, int buf) {
#pragma unroll
    for (int ks = 0; ks < 2; ++ks) {
#pragma unroll
      for (int fg = 0; fg < 2; ++fg) {
        const int f = fg * 4 + w;
        const size_t koff = (size_t)(kt + ks * 32 + lg * 8);
        const int dst = ((f * 2 + ks) * 64) * 8;  // wave-uniform LDS base
        gl_lds16(A + (size_t)(rowT + f * 16 + lr) * K + koff, &Al[buf][dst]);
        gl_lds16(Bm + (size_t)(colT + f * 16 + lr) * K + koff, &Bl[buf][dst]);
      }
    }
  };

  stage(0, 0);
  stage(64, 1);
  int cur = 0;
  for (int kt = 0; kt < K; kt += 64) {
    const bool notlast = (kt + 64 < K);
    // ---- phase ks = 0 ----
    if (notlast) asm volatile("s_waitcnt vmcnt(12)" ::: "memory");
    else         asm volatile("s_waitcnt vmcnt(4)" ::: "memory");
    __builtin_amdgcn_sched_barrier(0);
    __builtin_amdgcn_s_barrier();
    __builtin_amdgcn_sched_barrier(0);
    {
      bf16x8 af[4], bfv[4];
#pragma unroll
      for (int i = 0; i < 4; ++i) {
        af[i]  = *(const bf16x8*)(&Al[cur][(((wr * 4 + i) * 2 + 0) * 64 + l) * 8]);
        bfv[i] = *(const bf16x8*)(&Bl[cur][(((wc * 4 + i) * 2 + 0) * 64 + l) * 8]);
      }
      __builtin_amdgcn_s_setprio(1);
#pragma unroll
      for (int i = 0; i < 4; ++i)
#pragma unroll
        for (int j = 0; j < 4; ++j)
          acc[i][j] = mfma16(af[i], bfv[j], acc[i][j]);
      __builtin_amdgcn_s_setprio(0);
    }
    // ---- phase ks = 1 ----
    if (notlast) asm volatile("s_waitcnt vmcnt(8)" ::: "memory");
    else         asm volatile("s_waitcnt vmcnt(0)" ::: "memory");
    __builtin_amdgcn_sched_barrier(0);
    __builtin_amdgcn_s_barrier();
    __builtin_amdgcn_sched_barrier(0);
    {
      bf16x8 af[4], bfv[4];
#pragma unroll
      for (int i = 0; i < 4; ++i) {
        af[i]  = *(const bf16x8*)(&Al[cur][(((wr * 4 + i) * 2 + 1) * 64 + l) * 8]);
        bfv[i] = *(const bf16x8*)(&Bl[cur][(((wc * 4 + i) * 2 + 1) * 64 + l) * 8]);
      }
      __builtin_amdgcn_s_setprio(1);
#pragma unroll
      for (int i = 0; i < 4; ++i)
#pragma unroll
        for (int j = 0; j < 4; ++j)
          acc[i][j] = mfma16(af[i], bfv[j], acc[i][j]);
      __builtin_amdgcn_s_setprio(0);
    }
    __builtin_amdgcn_sched_barrier(0);
    __builtin_amdgcn_s_barrier();
    __builtin_amdgcn_sched_barrier(0);
    if (kt + 128 < K) stage(kt + 128, cur);
    cur ^= 1;
  }

  const int seg = colT >> 11;  // block-uniform
#pragma unroll
  for (int i = 0; i < 4; ++i) {
#pragma unroll
    for (int j = 0; j < 4; ++j) {
      const int col = colT + wc * 64 + j * 16 + lr;
#pragma unroll
      for (int e = 0; e < 4; ++e) {
        const int row = rowT + wr * 64 + i * 16 + lg * 4 + e;
        float v = acc[i][j][e];
        const int c = col & 2047;
        if (seg == 0)      Qo[(size_t)row * 2048 + c] = f2bf(v);
        else if (seg == 1) Ko[(size_t)row * 2048 + c] = f2bf(v);
        else               Vo[((size_t)((row >> 11) * 2048 + c)) * 2048 + (row & 2047)] = f2bf(v);
      }
    }
  }
}

// ======================= flash kernel: O + row stats (R13/R14) =======================
__global__ __launch_bounds__(256) void flash_kernel(const ushort* __restrict__ Qg,
                                                    const ushort* __restrict__ Kg,
                                                    const ushort* __restrict__ Vt,
                                                    ushort* __restrict__ Og,
                                                    float2* __restrict__ stats) {
  __shared__ __align__(16) ushort Kl[2][8192];
  __shared__ __align__(16) ushort Vl[2][8192];
  __shared__ __align__(16) ushort Pl[4][1024];

  // XCD-chunked swizzle: 512 blocks, 512%8==0
  const int flat = (int)(blockIdx.y * gridDim.x + blockIdx.x);
  const int swz = (flat & 7) * 64 + (flat >> 3);
  const int bx = swz & 15, bh = swz >> 4;
  const int b = bh >> 4, h = bh & 15;
  const int tid = (int)threadIdx.x, l = tid & 63, w = tid >> 6;
  const int lr = l & 15, lg = l >> 4;
  const float scale = 0.08838834764831845f;    // 1/sqrt(128)
  const float slope = exp2f(-(float)(h + 1));  // alibi slope
  const ushort* Kbase = Kg + ((size_t)b * 2048) * 2048 + h * 128;
  const ushort* Vbase = Vt + ((size_t)b * 2048 + h * 128) * 2048;

  for (int half = 0; half < 2; ++half) {
    const int qb = (half == 0) ? 31 - bx : bx;
    const int qr0 = qb * 64 + w * 16;

    bf16x8 qf[4];
#pragma unroll
    for (int ks = 0; ks < 4; ++ks)
      qf[ks] = *(const bf16x8*)(Qg + ((size_t)b * 2048 + qr0 + lr) * 2048 + h * 128 + ks * 32 + lg * 8);

    float runmax[4], runsum[4];
    f32x4 o[8] = {};
#pragma unroll
    for (int j = 0; j < 4; ++j) { runmax[j] = -__builtin_inff(); runsum[j] = 0.f; }

    auto stage = [&](int jt, int buf) {
#pragma unroll
      for (int q = 0; q < 4; ++q) {
        const int s = q * 256 + tid;
        const int sl = s & 63;
        const int cb = s >> 8, ks = (s >> 6) & 3;
        gl_lds16(Kbase + (size_t)(jt * 64 + cb * 16 + (sl & 15)) * 2048 + ks * 32 + (sl >> 4) * 8,
                 &Kl[buf][(size_t)(q * 256 + (tid & 192)) * 8]);
        const int db = s >> 7, k2 = (s >> 6) & 1;
        gl_lds16(Vbase + (size_t)(db * 16 + (sl & 15)) * 2048 + jt * 64 + k2 * 32 + (sl >> 4) * 8,
                 &Vl[buf][(size_t)(q * 256 + (tid & 192)) * 8]);
      }
    };

    stage(0, 0);  // prologue: 8 loads/wave in flight

    for (int jt = 0; jt <= qb; ++jt) {
      const int cur = jt & 1;
      if (jt < qb) {
        stage(jt + 1, cur ^ 1);                              // +8 loads (16 outstanding)
        asm volatile("s_waitcnt vmcnt(8)" ::: "memory");     // wait stage(jt) only
      } else {
        asm volatile("s_waitcnt vmcnt(0)" ::: "memory");     // last tile: full drain
      }
      __builtin_amdgcn_sched_barrier(0);
      __builtin_amdgcn_s_barrier();      // all waves' stage(jt) complete -> buf cur ready
      __builtin_amdgcn_sched_barrier(0);

      // QK^T + bias/mask
      f32x4 sc[4];
      __builtin_amdgcn_s_setprio(1);
#pragma unroll
      for (int cb = 0; cb < 4; ++cb) {
        f32x4 a = {};
#pragma unroll
        for (int ks = 0; ks < 4; ++ks) {
          bf16x8 kf = *(const bf16x8*)(&Kl[cur][((cb * 4 + ks) * 64 + l) * 8]);
          a = mfma16(qf[ks], kf, a);
        }
        sc[cb] = a;
      }
      __builtin_amdgcn_s_setprio(0);
#pragma unroll
      for (int cb = 0; cb < 4; ++cb) {
        const int kj = jt * 64 + cb * 16 + lr;
#pragma unroll
        for (int j = 0; j < 4; ++j) {
          const int qi = qr0 + lg * 4 + j;
          sc[cb][j] = (kj <= qi) ? sc[cb][j] * scale + slope * (float)(qi - kj) : -__builtin_inff();
        }
      }

      // deferred max: cheap per-lane growth check; full reduce+rescale only if needed
      float ml[4];
      bool grow = false;
#pragma unroll
      for (int j = 0; j < 4; ++j) {
        ml[j] = fmaxf(fmaxf(sc[0][j], sc[1][j]), fmaxf(sc[2][j], sc[3][j]));
        grow = grow || (ml[j] > runmax[j]);
      }
      if (__any(grow)) {
#pragma unroll
        for (int j = 0; j < 4; ++j) {
          float m = ml[j];
#pragma unroll
          for (int d = 1; d < 16; d <<= 1) m = fmaxf(m, __shfl_xor(m, d));
          const float nm = fmaxf(runmax[j], m);
          const float f = __expf(runmax[j] - nm);  // 0 on first tile, 1 if no growth
          runsum[j] *= f;
#pragma unroll
          for (int db = 0; db < 8; ++db) o[db][j] *= f;
          runmax[j] = nm;
        }
      }

      // p = exp(s - m); lane-partial row sums (reduced once at the end)
#pragma unroll
      for (int cb = 0; cb < 4; ++cb) {
        const int kc = cb * 16 + lr;
#pragma unroll
        for (int j = 0; j < 4; ++j) {
          const float p = __expf(sc[cb][j] - runmax[j]);
          runsum[j] += p;
          const int l2 = (((kc & 31) >> 3) << 4) | (lg * 4 + j);
          Pl[w][((kc >> 5) * 64 + l2) * 8 + (kc & 7)] = f2bf(p);
        }
      }

      // PV (P round-trips per-wave LDS into A-frag order; wave-local lgkmcnt)
      bf16x8 pf0 = *(const bf16x8*)(&Pl[w][(size_t)l * 8]);
      bf16x8 pf1 = *(const bf16x8*)(&Pl[w][(size_t)(64 + l) * 8]);
      __builtin_amdgcn_s_setprio(1);
#pragma unroll
      for (int db = 0; db < 8; ++db) {
        o[db] = mfma16(pf0, *(const bf16x8*)(&Vl[cur][((db * 2 + 0) * 64 + l) * 8]), o[db]);
        o[db] = mfma16(pf1, *(const bf16x8*)(&Vl[cur][((db * 2 + 1) * 64 + l) * 8]), o[db]);
      }
      __builtin_amdgcn_s_setprio(0);

      __builtin_amdgcn_sched_barrier(0);
      __builtin_amdgcn_s_barrier();      // all waves done reading buf cur before overwrite
      __builtin_amdgcn_sched_barrier(0);
    }

    // finalize: reduce row sums, write stats + O
#pragma unroll
    for (int j = 0; j < 4; ++j) {
      float s = runsum[j];
#pragma unroll
      for (int d = 1; d < 16; d <<= 1) s += __shfl_xor(s, d);
      const float iv = 1.0f / s;
      if (lr == 0) stats[(size_t)bh * 2048 + qr0 + lg * 4 + j] = make_float2(runmax[j], iv);
#pragma unroll
      for (int db = 0; db < 8; ++db) o[db][j] *= iv;
    }
#pragma unroll
    for (int db = 0; db < 8; ++db)
#pragma unroll
      for (int j = 0; j < 4; ++j)
        Og[((size_t)b * 2048 + qr0 + lg * 4 + j) * 2048 + h * 128 + db * 16 + lr] = f2bf(o[db][j]);
  }
}

// ======================= tail kernel: proj GEMM ∥ probs strips ∥ zero-fill ===========
// Blocks [0,512): projection GEMM (R14 graduated-vmcnt).
// Blocks [512,1024): probs strip-halves — pair {15-i, i}, 17 tiles of 128q x 64k each.
//   Q fragments in registers (per strip), K streamed via 2x16KB LDS dbuf with counted
//   vmcnt(8) (K loads issued BEFORE the flush stores each tile -> in-order retirement
//   means vmcnt(8) waits only the K load), P via dedicated 32KB LDS (R16 rotation).
// Blocks [1024,4864): 3840 zero-fill 128x128 tiles (backfill).
__global__ __launch_bounds__(256) void tail_kernel(const ushort* __restrict__ Ob,
                                                   const ushort* __restrict__ wob,
                                                   float* __restrict__ outp,
                                                   const float* __restrict__ bias,
                                                   const ushort* __restrict__ Qg,
                                                   const ushort* __restrict__ Kg,
                                                   const float2* __restrict__ stats,
                                                   float* __restrict__ attn_out) {
  __shared__ __align__(16) ushort SM[32768];  // 64 KB, shared by all paths
  const int blk = (int)blockIdx.x;
  const int tid = (int)threadIdx.x;
  const int l = tid & 63, w = tid >> 6;
  const int lr = l & 15, lg = l >> 4;

  if (blk < 512) {
    // ------- projection GEMM with graduated half-tile vmcnt (R14-identical)
    ushort (*Al)[8192] = (ushort(*)[8192])(SM);
    ushort (*Bl)[8192] = (ushort(*)[8192])(SM + 16384);
    const int wr = w >> 1, wc = w & 1;
    const int swz = (blk & 7) * 64 + (blk >> 3);  // 512 blocks, %8==0
    const int bx = swz & 15, by = swz >> 4;       // grid (16, 32)
    const int rowT = by * 128, colT = bx * 128;
    const int K = 2048;

    f32x4 acc[4][4] = {};

    auto stage = [&](int kt, int buf) {
#pragma unroll
      for (int ks = 0; ks < 2; ++ks) {
#pragma unroll
        for (int fg = 0; fg < 2; ++fg) {
          const int f = fg * 4 + w;
          const size_t koff = (size_t)(kt + ks * 32 + lg * 8);
          const int dst = ((f * 2 + ks) * 64) * 8;
          gl_lds16(Ob + (size_t)(rowT + f * 16 + lr) * K + koff, &Al[buf][dst]);
          gl_lds16(wob + (size_t)(colT + f * 16 + lr) * K + koff, &Bl[buf][dst]);
        }
      }
    };

    stage(0, 0);
    stage(64, 1);
    int cur = 0;
    for (int kt = 0; kt < K; kt += 64) {
      const bool notlast = (kt + 64 < K);
      if (notlast) asm volatile("s_waitcnt vmcnt(12)" ::: "memory");
      else         asm volatile("s_waitcnt vmcnt(4)" ::: "memory");
      __builtin_amdgcn_sched_barrier(0);
      __builtin_amdgcn_s_barrier();
      __builtin_amdgcn_sched_barrier(0);
      {
        bf16x8 af[4], bfv[4];
#pragma unroll
        for (int i = 0; i < 4; ++i) {
          af[i]  = *(const bf16x8*)(&Al[cur][(((wr * 4 + i) * 2 + 0) * 64 + l) * 8]);
          bfv[i] = *(const bf16x8*)(&Bl[cur][(((wc * 4 + i) * 2 + 0) * 64 + l) * 8]);
        }
        __builtin_amdgcn_s_setprio(1);
#pragma unroll
        for (int i = 0; i < 4; ++i)
#pragma unroll
          for (int j = 0; j < 4; ++j)
            acc[i][j] = mfma16(af[i], bfv[j], acc[i][j]);
        __builtin_amdgcn_s_setprio(0);
      }
      if (notlast) asm volatile("s_waitcnt vmcnt(8)" ::: "memory");
      else         asm volatile("s_waitcnt vmcnt(0)" ::: "memory");
      __builtin_amdgcn_sched_barrier(0);
      __builtin_amdgcn_s_barrier();
      __builtin_amdgcn_sched_barrier(0);
      {
        bf16x8 af[4], bfv[4];
#pragma unroll
        for (int i = 0; i < 4; ++i) {
          af[i]  = *(const bf16x8*)(&Al[cur][(((wr * 4 + i) * 2 + 1) * 64 + l) * 8]);
          bfv[i] = *(const bf16x8*)(&Bl[cur][(((wc * 4 + i) * 2 + 1) * 64 + l) * 8]);
        }
        __builtin_amdgcn_s_setprio(1);
#pragma unroll
        for (int i = 0; i < 4; ++i)
#pragma unroll
          for (int j = 0; j < 4; ++j)
            acc[i][j] = mfma16(af[i], bfv[j], acc[i][j]);
        __builtin_amdgcn_s_setprio(0);
      }
      __builtin_amdgcn_sched_barrier(0);
      __builtin_amdgcn_s_barrier();
      __builtin_amdgcn_sched_barrier(0);
      if (kt + 128 < K) stage(kt + 128, cur);
      cur ^= 1;
    }

#pragma unroll
    for (int i = 0; i < 4; ++i) {
#pragma unroll
      for (int j = 0; j < 4; ++j) {
        const int col = colT + wc * 64 + j * 16 + lr;
#pragma unroll
        for (int e = 0; e < 4; ++e) {
          const int row = rowT + wr * 64 + i * 16 + lg * 4 + e;
          __builtin_nontemporal_store(acc[i][j][e] + bias[col],
                                      &outp[(size_t)row * 2048 + col]);
        }
      }
    }
    return;
  }

  if (blk >= 1024) {  // ---------------- zero-fill: 3840 above-diagonal 128x128 tiles
    int rem = blk - 1024;
    const int bh = rem / 120;
    int t = rem % 120;
    int qb = 0;
    while (t >= 15 - qb) { t -= 15 - qb; ++qb; }
    const int kb = qb + 1 + t;
    float* base = attn_out + ((size_t)bh * 2048 + qb * 128) * 2048 + kb * 128;
    const f32x4 z = {0.f, 0.f, 0.f, 0.f};
#pragma unroll
    for (int it = 0; it < 16; ++it) {
      const int idx = it * 256 + tid;
      __builtin_nontemporal_store(z, (f32x4*)(base + (size_t)(idx >> 5) * 2048 + (idx & 31) * 4));
    }
    return;
  }

  // ---------------- probs strip-half: blocks [512, 1024) ----------------
  const int s = blk - 512;
  const int pi = s & 7, hh = (s >> 3) & 1, bh = s >> 4;
  const int b = bh >> 4, h = bh & 15;
  const int wr = w >> 1, wc = w & 1;
  const float scale = 0.08838834764831845f;
  const float slope = exp2f(-(float)(h + 1));
  ushort* Kb0 = SM;                      // 16 KB K tile buffers
  ushort* Kb1 = SM + 8192;
  float*  Pf  = (float*)(SM + 16384);    // 32 KB P buffer (128 x 64 f32)

  // stage one 64k x 128d K tile: 4 instr/thread, frag-order LDS [kf*4+ks][lane][8]
  auto stageK = [&](int kb, ushort* buf) {
#pragma unroll
    for (int a = 0; a < 4; ++a) {
      const int s2 = a * 256 + tid;
      const int sl = s2 & 63;
      gl_lds16(Kg + ((size_t)b * 2048 + kb * 64 + (s2 >> 8) * 16 + (sl & 15)) * 2048 +
                   h * 128 + ((s2 >> 6) & 3) * 32 + (sl >> 4) * 8,
               buf + (size_t)((s2 >> 6) * 64) * 8);
    }
  };

  for (int ph = 0; ph < 2; ++ph) {
    const int qb = (ph == 0) ? 15 - pi : pi;
    const int t0 = hh ? (qb + 1) : 0;  // half-strip tile range [t0, t0+T)
    const int T = qb + 1;

    // Q fragments for the whole strip (A operand; same pattern as flash's qf)
    bf16x8 qf[4][4];
#pragma unroll
    for (int i = 0; i < 4; ++i)
#pragma unroll
      for (int ks = 0; ks < 4; ++ks)
        qf[i][ks] = *(const bf16x8*)(Qg + ((size_t)b * 2048 + qb * 128 + (wr * 4 + i) * 16 + lr) * 2048 +
                                     h * 128 + ks * 32 + lg * 8);
    float2 st[4][4];
#pragma unroll
    for (int i = 0; i < 4; ++i)
#pragma unroll
      for (int e = 0; e < 4; ++e)
        st[i][e] = stats[(size_t)bh * 2048 + qb * 128 + wr * 64 + i * 16 + lg * 4 + e];

    stageK(t0, Kb0);
    __builtin_amdgcn_sched_barrier(0);

    for (int t = 0; t < T; ++t) {
      const int kb = t0 + t;
      ushort* bufc = (t & 1) ? Kb1 : Kb0;
      ushort* bufn = (t & 1) ? Kb0 : Kb1;
      // K(kb) ready: first tile drains (Q + K0 + stale stores); steady state vmcnt(8)
      // (K(kb) is oldest among {K(kb), prev-tile's 8 flush stores}).
      if (t == 0) asm volatile("s_waitcnt vmcnt(0)" ::: "memory");
      else        asm volatile("s_waitcnt vmcnt(8)" ::: "memory");
      __builtin_amdgcn_sched_barrier(0);
      __builtin_amdgcn_s_barrier();   // also guards: prev flush done before P re-write
      __builtin_amdgcn_sched_barrier(0);

      f32x4 acc[4][2] = {};
#pragma unroll
      for (int ks = 0; ks < 4; ++ks) {
        bf16x8 bfv[2];
#pragma unroll
        for (int j = 0; j < 2; ++j)
          bfv[j] = *(const bf16x8*)(bufc + (((wc * 2 + j) * 4 + ks) * 64 + l) * 8);
        __builtin_amdgcn_s_setprio(1);
#pragma unroll
        for (int i = 0; i < 4; ++i)
#pragma unroll
          for (int j = 0; j < 2; ++j)
            acc[i][j] = mfma16(qf[i][ks], bfv[j], acc[i][j]);
        __builtin_amdgcn_s_setprio(0);
      }

      // issue next K stage BEFORE the flush stores (keeps K oldest in vmcnt FIFO)
      if (t + 1 < T) stageK(kb + 1, bufn);
      __builtin_amdgcn_sched_barrier(0);

      // P epilogue into Pf (rotation layout: 2-way max bank conflict)
#pragma unroll
      for (int i = 0; i < 4; ++i) {
#pragma unroll
        for (int j = 0; j < 2; ++j) {
          const int cl = wc * 32 + j * 16 + lr;
          const int kj = kb * 64 + cl;
#pragma unroll
          for (int e = 0; e < 4; ++e) {
            const int rl = wr * 64 + i * 16 + lg * 4 + e;
            const int qi = qb * 128 + rl;
            const float sv = acc[i][j][e] * scale + slope * (float)(qi - kj);
            float p = __expf(sv - st[i][e].x) * st[i][e].y;
            if (kj > qi) p = 0.f;
            Pf[rl * 64 + ((cl + (rl << 2)) & 63)] = p;
          }
        }
      }
      __builtin_amdgcn_sched_barrier(0);
      __builtin_amdgcn_s_barrier();   // all P written
      __builtin_amdgcn_sched_barrier(0);

      // flush: 8 x f32x4 NT per thread, 256B contiguous row segments
      float* gbase = attn_out + ((size_t)bh * 2048 + qb * 128) * 2048 + kb * 64;
#pragma unroll
      for (int it = 0; it < 8; ++it) {
        const int idx = it * 256 + tid;
        const int row = idx >> 4, c4 = (idx & 15) << 2;
        f32x4 v = *(const f32x4*)(&Pf[row * 64 + ((c4 + (row << 2)) & 63)]);
        __builtin_nontemporal_store(v, (f32x4*)(gbase + (size_t)row * 2048 + c4));
      }
    }
  }
}

// ======================= launch =======================
extern "C" void kernel_launch(void* const* d_in, const int* in_sizes, int n_in,
                              void* d_out, int out_size, void* d_ws, size_t ws_size,
                              hipStream_t stream) {
  (void)in_sizes; (void)n_in; (void)out_size; (void)ws_size;
  const float* x  = (const float*)d_in[0];
  const float* Wq = (const float*)d_in[1];
  const float* Wk = (const float*)d_in[2];
  const float* Wv = (const float*)d_in[3];
  const float* Wo = (const float*)d_in[4];
  const float* bo = (const float*)d_in[5];

  float* outp  = (float*)d_out;                      // (B,T,C) f32
  float* attnp = outp + (size_t)4096 * 2048;         // (B,H,T,T) f32

  char* ws = (char*)d_ws;                            // 112 MB used
  ushort* xb   = (ushort*)(ws);                      // x bf16              (16 MB)
  ushort* wqkv = (ushort*)(ws + (16ull << 20));      // [Wq;Wk;Wv] bf16     (24 MB)
  ushort* wob  = (ushort*)(ws + (40ull << 20));      // Wo bf16             (8 MB)
  ushort* Qb   = (ushort*)(ws + (48ull << 20));      // Q bf16              (16 MB)
  ushort* Kb   = (ushort*)(ws + (64ull << 20));      // K bf16              (16 MB)
  ushort* Vtb  = (ushort*)(ws + (80ull << 20));      // V^T bf16            (16 MB)
  ushort* Ob   = (ushort*)(ws + (96ull << 20));      // attn@V bf16         (16 MB)
  // stats (m, 1/sum) per row: 512 KB. Reuses xb (dead after QKV GEMM, recast each call).
  float2* stats = (float2*)(ws);

  cast_all_kernel<<<6144, 256, 0, stream>>>(
      (const float4*)x, (const float4*)Wq, (const float4*)Wk, (const float4*)Wv,
      (const float4*)Wo, (ushort4*)xb, (ushort4*)wqkv, (ushort4*)(wqkv + 4194304),
      (ushort4*)(wqkv + 2 * 4194304), (ushort4*)wob);

  // fused QKV: M=4096, N=6144, K=2048
  gemm_qkv<<<dim3(48, 32), 256, 0, stream>>>(xb, wqkv, Qb, Kb, Vtb, 4096, 6144, 2048);

  flash_kernel<<<dim3(16, 32), 256, 0, stream>>>(Qb, Kb, Vtb, Ob, stats);

  // merged tail: 512 proj + 512 probs strip-halves + 3840 zero-fill
  tail_kernel<<<4864, 256, 0, stream>>>(Ob, wob, outp, bo, Qb, Kb, stats, attnp);
}

// Round 20
// 500.932 us; speedup vs baseline: 1.0473x; 1.0473x over previous
//
#include <hip/hip_runtime.h>
#include <hip/hip_bf16.h>

#define DEVINL __device__ __forceinline__

typedef __attribute__((ext_vector_type(8))) short bf16x8;
typedef __attribute__((ext_vector_type(4))) float f32x4;

// f32 -> bf16 round-nearest-even (bit manipulation; values are finite)
DEVINL ushort f2bf(float f) {
  unsigned u = __float_as_uint(f);
  u += 0x7fffu + ((u >> 16) & 1u);
  return (ushort)(u >> 16);
}

DEVINL void gl_lds16(const void* g, void* lds) {
  __builtin_amdgcn_global_load_lds(
      (const __attribute__((address_space(1))) void*)g,
      (__attribute__((address_space(3))) void*)lds, 16, 0, 0);
}

DEVINL f32x4 mfma16(bf16x8 a, bf16x8 b, f32x4 c) {
  return __builtin_amdgcn_mfma_f32_16x16x32_bf16(a, b, c, 0, 0, 0);
}

// ======================= fused cast f32 -> bf16 (exact shapes) =======================
__global__ __launch_bounds__(256) void cast_all_kernel(const float4* __restrict__ x,
                                                       const float4* __restrict__ wq,
                                                       const float4* __restrict__ wk,
                                                       const float4* __restrict__ wv,
                                                       const float4* __restrict__ wo,
                                                       ushort4* __restrict__ xb,
                                                       ushort4* __restrict__ wqb,
                                                       ushort4* __restrict__ wkb,
                                                       ushort4* __restrict__ wvb,
                                                       ushort4* __restrict__ wob) {
  const int blk = (int)blockIdx.x;
  const float4* src;
  ushort4* dst;
  int base;
  if (blk < 2048)      { src = x;  dst = xb;  base = blk; }
  else if (blk < 3072) { src = wq; dst = wqb; base = blk - 2048; }
  else if (blk < 4096) { src = wk; dst = wkb; base = blk - 3072; }
  else if (blk < 5120) { src = wv; dst = wvb; base = blk - 4096; }
  else                 { src = wo; dst = wob; base = blk - 5120; }
  const int idx0 = base * 1024 + (int)threadIdx.x;
#pragma unroll
  for (int i = 0; i < 4; ++i) {
    const int idx = idx0 + i * 256;
    float4 v = src[idx];
    dst[idx] = make_ushort4(f2bf(v.x), f2bf(v.y), f2bf(v.z), f2bf(v.w));
  }
}

// ======================= QKV GEMM: 128^2 tile, graduated half-tile vmcnt (R14) ========
__global__ __launch_bounds__(256) void gemm_qkv(const ushort* __restrict__ A,
                                                const ushort* __restrict__ Bm,
                                                ushort* __restrict__ Qo,
                                                ushort* __restrict__ Ko,
                                                ushort* __restrict__ Vo,
                                                int M, int N, int K) {
  __shared__ __align__(16) ushort Al[2][8192];  // [f:8][ks:2][lane:64][8]
  __shared__ __align__(16) ushort Bl[2][8192];
  const int tid = (int)threadIdx.x;
  const int l = tid & 63, w = tid >> 6;
  const int wr = w >> 1, wc = w & 1;
  const int lr = l & 15, lg = l >> 4;

  // bijective XCD-chunked swizzle (nwg % 8 == 0)
  const int nwg = (int)(gridDim.x * gridDim.y);
  const int flat = (int)(blockIdx.y * gridDim.x + blockIdx.x);
  const int swz = (flat & 7) * (nwg >> 3) + (flat >> 3);
  const int bx = swz % (int)gridDim.x, by = swz / (int)gridDim.x;
  const int rowT = by * 128, colT = bx * 128;

  f32x4 acc[4][4] = {};

  // wave w stages slice f = fg*4 + w for each (ks, fg); 8 instr/thread per tile
  auto stage = [&](int kt, int buf) {
#pragma unroll
    for (int ks = 0; ks < 2; ++ks) {
#pragma unroll
      for (int fg = 0; fg < 2; ++fg) {
        const int f = fg * 4 + w;
        const size_t koff = (size_t)(kt + ks * 32 + lg * 8);
        const int dst = ((f * 2 + ks) * 64) * 8;  // wave-uniform LDS base
        gl_lds16(A + (size_t)(rowT + f * 16 + lr) * K + koff, &Al[buf][dst]);
        gl_lds16(Bm + (size_t)(colT + f * 16 + lr) * K + koff, &Bl[buf][dst]);
      }
    }
  };

  stage(0, 0);
  stage(64, 1);
  int cur = 0;
  for (int kt = 0; kt < K; kt += 64) {
    const bool notlast = (kt + 64 < K);
    // ---- phase ks = 0 ----
    if (notlast) asm volatile("s_waitcnt vmcnt(12)" ::: "memory");
    else         asm volatile("s_waitcnt vmcnt(4)" ::: "memory");
    __builtin_amdgcn_sched_barrier(0);
    __builtin_amdgcn_s_barrier();
    __builtin_amdgcn_sched_barrier(0);
    {
      bf16x8 af[4], bfv[4];
#pragma unroll
      for (int i = 0; i < 4; ++i) {
        af[i]  = *(const bf16x8*)(&Al[cur][(((wr * 4 + i) * 2 + 0) * 64 + l) * 8]);
        bfv[i] = *(const bf16x8*)(&Bl[cur][(((wc * 4 + i) * 2 + 0) * 64 + l) * 8]);
      }
      __builtin_amdgcn_s_setprio(1);
#pragma unroll
      for (int i = 0; i < 4; ++i)
#pragma unroll
        for (int j = 0; j < 4; ++j)
          acc[i][j] = mfma16(af[i], bfv[j], acc[i][j]);
      __builtin_amdgcn_s_setprio(0);
    }
    // ---- phase ks = 1 ----
    if (notlast) asm volatile("s_waitcnt vmcnt(8)" ::: "memory");
    else         asm volatile("s_waitcnt vmcnt(0)" ::: "memory");
    __builtin_amdgcn_sched_barrier(0);
    __builtin_amdgcn_s_barrier();
    __builtin_amdgcn_sched_barrier(0);
    {
      bf16x8 af[4], bfv[4];
#pragma unroll
      for (int i = 0; i < 4; ++i) {
        af[i]  = *(const bf16x8*)(&Al[cur][(((wr * 4 + i) * 2 + 1) * 64 + l) * 8]);
        bfv[i] = *(const bf16x8*)(&Bl[cur][(((wc * 4 + i) * 2 + 1) * 64 + l) * 8]);
      }
      __builtin_amdgcn_s_setprio(1);
#pragma unroll
      for (int i = 0; i < 4; ++i)
#pragma unroll
        for (int j = 0; j < 4; ++j)
          acc[i][j] = mfma16(af[i], bfv[j], acc[i][j]);
      __builtin_amdgcn_s_setprio(0);
    }
    __builtin_amdgcn_sched_barrier(0);
    __builtin_amdgcn_s_barrier();
    __builtin_amdgcn_sched_barrier(0);
    if (kt + 128 < K) stage(kt + 128, cur);
    cur ^= 1;
  }

  const int seg = colT >> 11;  // block-uniform
#pragma unroll
  for (int i = 0; i < 4; ++i) {
#pragma unroll
    for (int j = 0; j < 4; ++j) {
      const int col = colT + wc * 64 + j * 16 + lr;
#pragma unroll
      for (int e = 0; e < 4; ++e) {
        const int row = rowT + wr * 64 + i * 16 + lg * 4 + e;
        float v = acc[i][j][e];
        const int c = col & 2047;
        if (seg == 0)      Qo[(size_t)row * 2048 + c] = f2bf(v);
        else if (seg == 1) Ko[(size_t)row * 2048 + c] = f2bf(v);
        else               Vo[((size_t)((row >> 11) * 2048 + c)) * 2048 + (row & 2047)] = f2bf(v);
      }
    }
  }
}

// ======================= flash kernel: O + row stats (R13/R14) =======================
__global__ __launch_bounds__(256) void flash_kernel(const ushort* __restrict__ Qg,
                                                    const ushort* __restrict__ Kg,
                                                    const ushort* __restrict__ Vt,
                                                    ushort* __restrict__ Og,
                                                    float2* __restrict__ stats) {
  __shared__ __align__(16) ushort Kl[2][8192];
  __shared__ __align__(16) ushort Vl[2][8192];
  __shared__ __align__(16) ushort Pl[4][1024];

  // XCD-chunked swizzle: 512 blocks, 512%8==0
  const int flat = (int)(blockIdx.y * gridDim.x + blockIdx.x);
  const int swz = (flat & 7) * 64 + (flat >> 3);
  const int bx = swz & 15, bh = swz >> 4;
  const int b = bh >> 4, h = bh & 15;
  const int tid = (int)threadIdx.x, l = tid & 63, w = tid >> 6;
  const int lr = l & 15, lg = l >> 4;
  const float scale = 0.08838834764831845f;    // 1/sqrt(128)
  const float slope = exp2f(-(float)(h + 1));  // alibi slope
  const ushort* Kbase = Kg + ((size_t)b * 2048) * 2048 + h * 128;
  const ushort* Vbase = Vt + ((size_t)b * 2048 + h * 128) * 2048;

  for (int half = 0; half < 2; ++half) {
    const int qb = (half == 0) ? 31 - bx : bx;
    const int qr0 = qb * 64 + w * 16;

    bf16x8 qf[4];
#pragma unroll
    for (int ks = 0; ks < 4; ++ks)
      qf[ks] = *(const bf16x8*)(Qg + ((size_t)b * 2048 + qr0 + lr) * 2048 + h * 128 + ks * 32 + lg * 8);

    float runmax[4], runsum[4];
    f32x4 o[8] = {};
#pragma unroll
    for (int j = 0; j < 4; ++j) { runmax[j] = -__builtin_inff(); runsum[j] = 0.f; }

    auto stage = [&](int jt, int buf) {
#pragma unroll
      for (int q = 0; q < 4; ++q) {
        const int s = q * 256 + tid;
        const int sl = s & 63;
        const int cb = s >> 8, ks = (s >> 6) & 3;
        gl_lds16(Kbase + (size_t)(jt * 64 + cb * 16 + (sl & 15)) * 2048 + ks * 32 + (sl >> 4) * 8,
                 &Kl[buf][(size_t)(q * 256 + (tid & 192)) * 8]);
        const int db = s >> 7, k2 = (s >> 6) & 1;
        gl_lds16(Vbase + (size_t)(db * 16 + (sl & 15)) * 2048 + jt * 64 + k2 * 32 + (sl >> 4) * 8,
                 &Vl[buf][(size_t)(q * 256 + (tid & 192)) * 8]);
      }
    };

    stage(0, 0);  // prologue: 8 loads/wave in flight

    for (int jt = 0; jt <= qb; ++jt) {
      const int cur = jt & 1;
      if (jt < qb) {
        stage(jt + 1, cur ^ 1);                              // +8 loads (16 outstanding)
        asm volatile("s_waitcnt vmcnt(8)" ::: "memory");     // wait stage(jt) only
      } else {
        asm volatile("s_waitcnt vmcnt(0)" ::: "memory");     // last tile: full drain
      }
      __builtin_amdgcn_sched_barrier(0);
      __builtin_amdgcn_s_barrier();      // all waves' stage(jt) complete -> buf cur ready
      __builtin_amdgcn_sched_barrier(0);

      // QK^T + bias/mask
      f32x4 sc[4];
      __builtin_amdgcn_s_setprio(1);
#pragma unroll
      for (int cb = 0; cb < 4; ++cb) {
        f32x4 a = {};
#pragma unroll
        for (int ks = 0; ks < 4; ++ks) {
          bf16x8 kf = *(const bf16x8*)(&Kl[cur][((cb * 4 + ks) * 64 + l) * 8]);
          a = mfma16(qf[ks], kf, a);
        }
        sc[cb] = a;
      }
      __builtin_amdgcn_s_setprio(0);
#pragma unroll
      for (int cb = 0; cb < 4; ++cb) {
        const int kj = jt * 64 + cb * 16 + lr;
#pragma unroll
        for (int j = 0; j < 4; ++j) {
          const int qi = qr0 + lg * 4 + j;
          sc[cb][j] = (kj <= qi) ? sc[cb][j] * scale + slope * (float)(qi - kj) : -__builtin_inff();
        }
      }

      // deferred max: cheap per-lane growth check; full reduce+rescale only if needed
      float ml[4];
      bool grow = false;
#pragma unroll
      for (int j = 0; j < 4; ++j) {
        ml[j] = fmaxf(fmaxf(sc[0][j], sc[1][j]), fmaxf(sc[2][j], sc[3][j]));
        grow = grow || (ml[j] > runmax[j]);
      }
      if (__any(grow)) {
#pragma unroll
        for (int j = 0; j < 4; ++j) {
          float m = ml[j];
#pragma unroll
          for (int d = 1; d < 16; d <<= 1) m = fmaxf(m, __shfl_xor(m, d));
          const float nm = fmaxf(runmax[j], m);
          const float f = __expf(runmax[j] - nm);  // 0 on first tile, 1 if no growth
          runsum[j] *= f;
#pragma unroll
          for (int db = 0; db < 8; ++db) o[db][j] *= f;
          runmax[j] = nm;
        }
      }

      // p = exp(s - m); lane-partial row sums (reduced once at the end)
#pragma unroll
      for (int cb = 0; cb < 4; ++cb) {
        const int kc = cb * 16 + lr;
#pragma unroll
        for (int j = 0; j < 4; ++j) {
          const float p = __expf(sc[cb][j] - runmax[j]);
          runsum[j] += p;
          const int l2 = (((kc & 31) >> 3) << 4) | (lg * 4 + j);
          Pl[w][((kc >> 5) * 64 + l2) * 8 + (kc & 7)] = f2bf(p);
        }
      }

      // PV (P round-trips per-wave LDS into A-frag order; wave-local lgkmcnt)
      bf16x8 pf0 = *(const bf16x8*)(&Pl[w][(size_t)l * 8]);
      bf16x8 pf1 = *(const bf16x8*)(&Pl[w][(size_t)(64 + l) * 8]);
      __builtin_amdgcn_s_setprio(1);
#pragma unroll
      for (int db = 0; db < 8; ++db) {
        o[db] = mfma16(pf0, *(const bf16x8*)(&Vl[cur][((db * 2 + 0) * 64 + l) * 8]), o[db]);
        o[db] = mfma16(pf1, *(const bf16x8*)(&Vl[cur][((db * 2 + 1) * 64 + l) * 8]), o[db]);
      }
      __builtin_amdgcn_s_setprio(0);

      __builtin_amdgcn_sched_barrier(0);
      __builtin_amdgcn_s_barrier();      // all waves done reading buf cur before overwrite
      __builtin_amdgcn_sched_barrier(0);
    }

    // finalize: reduce row sums, write stats + O
#pragma unroll
    for (int j = 0; j < 4; ++j) {
      float s = runsum[j];
#pragma unroll
      for (int d = 1; d < 16; d <<= 1) s += __shfl_xor(s, d);
      const float iv = 1.0f / s;
      if (lr == 0) stats[(size_t)bh * 2048 + qr0 + lg * 4 + j] = make_float2(runmax[j], iv);
#pragma unroll
      for (int db = 0; db < 8; ++db) o[db][j] *= iv;
    }
#pragma unroll
    for (int db = 0; db < 8; ++db)
#pragma unroll
      for (int j = 0; j < 4; ++j)
        Og[((size_t)b * 2048 + qr0 + lg * 4 + j) * 2048 + h * 128 + db * 16 + lr] = f2bf(o[db][j]);
  }
}

// ======================= tail kernel: proj GEMM ∥ probs (R16 proven) =================
// Blocks [0,512): projection GEMM (R14 graduated-vmcnt). Blocks [512,8704): probs tiles.
// probs epilogue routes P through the dead Q/K LDS (row-rotation layout, 2-way max bank
// conflict = free) so global NT stores become f32x4 with 512B-contiguous row segments.
__global__ __launch_bounds__(256) void tail_kernel(const ushort* __restrict__ Ob,
                                                   const ushort* __restrict__ wob,
                                                   float* __restrict__ outp,
                                                   const float* __restrict__ bias,
                                                   const ushort* __restrict__ Qg,
                                                   const ushort* __restrict__ Kg,
                                                   const float2* __restrict__ stats,
                                                   float* __restrict__ attn_out) {
  __shared__ __align__(16) ushort SM[32768];  // 64 KB, shared by both paths
  const int blk = (int)blockIdx.x;
  const int tid = (int)threadIdx.x;
  const int l = tid & 63, w = tid >> 6;
  const int lr = l & 15, lg = l >> 4;

  if (blk < 512) {
    // ------- projection GEMM with graduated half-tile vmcnt (R14-identical)
    ushort (*Al)[8192] = (ushort(*)[8192])(SM);
    ushort (*Bl)[8192] = (ushort(*)[8192])(SM + 16384);
    const int wr = w >> 1, wc = w & 1;
    const int swz = (blk & 7) * 64 + (blk >> 3);  // 512 blocks, %8==0
    const int bx = swz & 15, by = swz >> 4;       // grid (16, 32)
    const int rowT = by * 128, colT = bx * 128;
    const int K = 2048;

    f32x4 acc[4][4] = {};

    auto stage = [&](int kt, int buf) {
#pragma unroll
      for (int ks = 0; ks < 2; ++ks) {
#pragma unroll
        for (int fg = 0; fg < 2; ++fg) {
          const int f = fg * 4 + w;
          const size_t koff = (size_t)(kt + ks * 32 + lg * 8);
          const int dst = ((f * 2 + ks) * 64) * 8;
          gl_lds16(Ob + (size_t)(rowT + f * 16 + lr) * K + koff, &Al[buf][dst]);
          gl_lds16(wob + (size_t)(colT + f * 16 + lr) * K + koff, &Bl[buf][dst]);
        }
      }
    };

    stage(0, 0);
    stage(64, 1);
    int cur = 0;
    for (int kt = 0; kt < K; kt += 64) {
      const bool notlast = (kt + 64 < K);
      if (notlast) asm volatile("s_waitcnt vmcnt(12)" ::: "memory");
      else         asm volatile("s_waitcnt vmcnt(4)" ::: "memory");
      __builtin_amdgcn_sched_barrier(0);
      __builtin_amdgcn_s_barrier();
      __builtin_amdgcn_sched_barrier(0);
      {
        bf16x8 af[4], bfv[4];
#pragma unroll
        for (int i = 0; i < 4; ++i) {
          af[i]  = *(const bf16x8*)(&Al[cur][(((wr * 4 + i) * 2 + 0) * 64 + l) * 8]);
          bfv[i] = *(const bf16x8*)(&Bl[cur][(((wc * 4 + i) * 2 + 0) * 64 + l) * 8]);
        }
        __builtin_amdgcn_s_setprio(1);
#pragma unroll
        for (int i = 0; i < 4; ++i)
#pragma unroll
          for (int j = 0; j < 4; ++j)
            acc[i][j] = mfma16(af[i], bfv[j], acc[i][j]);
        __builtin_amdgcn_s_setprio(0);
      }
      if (notlast) asm volatile("s_waitcnt vmcnt(8)" ::: "memory");
      else         asm volatile("s_waitcnt vmcnt(0)" ::: "memory");
      __builtin_amdgcn_sched_barrier(0);
      __builtin_amdgcn_s_barrier();
      __builtin_amdgcn_sched_barrier(0);
      {
        bf16x8 af[4], bfv[4];
#pragma unroll
        for (int i = 0; i < 4; ++i) {
          af[i]  = *(const bf16x8*)(&Al[cur][(((wr * 4 + i) * 2 + 1) * 64 + l) * 8]);
          bfv[i] = *(const bf16x8*)(&Bl[cur][(((wc * 4 + i) * 2 + 1) * 64 + l) * 8]);
        }
        __builtin_amdgcn_s_setprio(1);
#pragma unroll
        for (int i = 0; i < 4; ++i)
#pragma unroll
          for (int j = 0; j < 4; ++j)
            acc[i][j] = mfma16(af[i], bfv[j], acc[i][j]);
        __builtin_amdgcn_s_setprio(0);
      }
      __builtin_amdgcn_sched_barrier(0);
      __builtin_amdgcn_s_barrier();
      __builtin_amdgcn_sched_barrier(0);
      if (kt + 128 < K) stage(kt + 128, cur);
      cur ^= 1;
    }

#pragma unroll
    for (int i = 0; i < 4; ++i) {
#pragma unroll
      for (int j = 0; j < 4; ++j) {
        const int col = colT + wc * 64 + j * 16 + lr;
#pragma unroll
        for (int e = 0; e < 4; ++e) {
          const int row = rowT + wr * 64 + i * 16 + lg * 4 + e;
          __builtin_nontemporal_store(acc[i][j][e] + bias[col],
                                      &outp[(size_t)row * 2048 + col]);
        }
      }
    }
    return;
  }

  // ---------------- probs path: blocks 512.. map to (kb, qb, bh)
  const int rem = blk - 512;
  const int kb = rem & 15, qb = (rem >> 4) & 15, bh = rem >> 8;

  if (kb > qb) {  // strictly-above-diagonal tile: exact zeros (512B segments)
    float* base = attn_out + ((size_t)bh * 2048 + qb * 128) * 2048 + kb * 128;
    const f32x4 z = {0.f, 0.f, 0.f, 0.f};
#pragma unroll
    for (int it = 0; it < 16; ++it) {
      const int idx = it * 256 + tid;
      __builtin_nontemporal_store(z, (f32x4*)(base + (size_t)(idx >> 5) * 2048 + (idx & 31) * 4));
    }
    return;
  }

  ushort* Ql = SM;
  ushort* Kl = SM + 16384;
  float* Pf = (float*)SM;  // reused after Q/K are consumed
  const int b = bh >> 4, h = bh & 15;
  const int wr = w >> 1, wc = w & 1;
  const float scale = 0.08838834764831845f;
  const float slope = exp2f(-(float)(h + 1));

#pragma unroll
  for (int q = 0; q < 8; ++q) {
    const int s = q * 256 + tid;
    const int sl = s & 63, rb = s >> 8, ks = (s >> 6) & 3;
    const size_t koff = (size_t)(h * 128 + ks * 32 + (sl >> 4) * 8);
    gl_lds16(Qg + ((size_t)b * 2048 + qb * 128 + rb * 16 + (sl & 15)) * 2048 + koff,
             Ql + (size_t)(q * 256 + (tid & 192)) * 8);
    gl_lds16(Kg + ((size_t)b * 2048 + kb * 128 + rb * 16 + (sl & 15)) * 2048 + koff,
             Kl + (size_t)(q * 256 + (tid & 192)) * 8);
  }
  __syncthreads();

  f32x4 acc[4][4] = {};
#pragma unroll
  for (int ks = 0; ks < 4; ++ks) {
    bf16x8 af[4], bfv[4];
#pragma unroll
    for (int i = 0; i < 4; ++i) {
      af[i]  = *(const bf16x8*)(Ql + (((wr * 4 + i) * 4 + ks) * 64 + l) * 8);
      bfv[i] = *(const bf16x8*)(Kl + (((wc * 4 + i) * 4 + ks) * 64 + l) * 8);
    }
#pragma unroll
    for (int i = 0; i < 4; ++i)
#pragma unroll
      for (int j = 0; j < 4; ++j)
        acc[i][j] = mfma16(af[i], bfv[j], acc[i][j]);
  }

  float2 st[4][4];
#pragma unroll
  for (int i = 0; i < 4; ++i)
#pragma unroll
    for (int e = 0; e < 4; ++e)
      st[i][e] = stats[(size_t)bh * 2048 + qb * 128 + wr * 64 + i * 16 + lg * 4 + e];

  __syncthreads();  // all waves' Q/K ds_reads consumed -> safe to overwrite SM with P

#pragma unroll
  for (int i = 0; i < 4; ++i) {
#pragma unroll
    for (int j = 0; j < 4; ++j) {
      const int cl = wc * 64 + j * 16 + lr;   // local key col
      const int kj = kb * 128 + cl;
#pragma unroll
      for (int e = 0; e < 4; ++e) {
        const int rl = wr * 64 + i * 16 + lg * 4 + e;  // local query row
        const int qi = qb * 128 + rl;
        const float sv = acc[i][j][e] * scale + slope * (float)(qi - kj);
        float p = __expf(sv - st[i][e].x) * st[i][e].y;
        if (kj > qi) p = 0.f;  // only possible when kb == qb
        Pf[rl * 128 + ((cl + (rl << 2)) & 127)] = p;  // row-rotation: 2-way max conflict
      }
    }
  }
  __syncthreads();

  float* gbase = attn_out + ((size_t)bh * 2048 + qb * 128) * 2048 + kb * 128;
#pragma unroll
  for (int it = 0; it < 16; ++it) {
    const int idx = it * 256 + tid;
    const int row = idx >> 5, c4 = (idx & 31) << 2;
    f32x4 v = *(const f32x4*)(&Pf[row * 128 + ((c4 + (row << 2)) & 127)]);
    __builtin_nontemporal_store(v, (f32x4*)(gbase + (size_t)row * 2048 + c4));
  }
}

// ======================= launch =======================
extern "C" void kernel_launch(void* const* d_in, const int* in_sizes, int n_in,
                              void* d_out, int out_size, void* d_ws, size_t ws_size,
                              hipStream_t stream) {
  (void)in_sizes; (void)n_in; (void)out_size; (void)ws_size;
  const float* x  = (const float*)d_in[0];
  const float* Wq = (const float*)d_in[1];
  const float* Wk = (const float*)d_in[2];
  const float* Wv = (const float*)d_in[3];
  const float* Wo = (const float*)d_in[4];
  const float* bo = (const float*)d_in[5];

  float* outp  = (float*)d_out;                      // (B,T,C) f32
  float* attnp = outp + (size_t)4096 * 2048;         // (B,H,T,T) f32

  char* ws = (char*)d_ws;                            // 112 MB used
  ushort* xb   = (ushort*)(ws);                      // x bf16              (16 MB)
  ushort* wqkv = (ushort*)(ws + (16ull << 20));      // [Wq;Wk;Wv] bf16     (24 MB)
  ushort* wob  = (ushort*)(ws + (40ull << 20));      // Wo bf16             (8 MB)
  ushort* Qb   = (ushort*)(ws + (48ull << 20));      // Q bf16              (16 MB)
  ushort* Kb   = (ushort*)(ws + (64ull << 20));      // K bf16              (16 MB)
  ushort* Vtb  = (ushort*)(ws + (80ull << 20));      // V^T bf16            (16 MB)
  ushort* Ob   = (ushort*)(ws + (96ull << 20));      // attn@V bf16         (16 MB)
  // stats (m, 1/sum) per row: 512 KB. Reuses xb (dead after QKV GEMM, recast each call).
  float2* stats = (float2*)(ws);

  cast_all_kernel<<<6144, 256, 0, stream>>>(
      (const float4*)x, (const float4*)Wq, (const float4*)Wk, (const float4*)Wv,
      (const float4*)Wo, (ushort4*)xb, (ushort4*)wqkv, (ushort4*)(wqkv + 4194304),
      (ushort4*)(wqkv + 2 * 4194304), (ushort4*)wob);

  // fused QKV: M=4096, N=6144, K=2048
  gemm_qkv<<<dim3(48, 32), 256, 0, stream>>>(xb, wqkv, Qb, Kb, Vtb, 4096, 6144, 2048);

  flash_kernel<<<dim3(16, 32), 256, 0, stream>>>(Qb, Kb, Vtb, Ob, stats);

  // merged tail: 512 proj blocks + 8192 probs blocks
  tail_kernel<<<8704, 256, 0, stream>>>(Ob, wob, outp, bo, Qb, Kb, stats, attnp);
}